// Round 10
// baseline (86.042 us; speedup 1.0000x reference)
//
#include <hip/hip_runtime.h>

#define N 4096
#define BATCH 8192
#define NROWS 4
#define TPB 512
#define D2S 68              // padded d2 stride (floats): 64+4 -> 2-way banks max
#define D3S 544             // d3 stride = 8*68
#define ROWBUF 4352         // 8*544 floats per row buffer
#define NWS_F4 (9 * 2048)   // permuted twiddles, layers 3..11

typedef float v4f __attribute__((ext_vector_type(4)));

// One butterfly sub-layer on the in-register 8-dim. k=0,1,2 -> pair distance 4,2,1.
__device__ __forceinline__ void bfly(float (&v)[NROWS][8], const float4 (&w)[4], const int k) {
    const int bit = 2 - k;
    const int d = 1 << bit;
    #pragma unroll
    for (int pc = 0; pc < 4; ++pc) {
        const int lo = ((pc >> bit) << (bit + 1)) | (pc & (d - 1));
        const int hi = lo + d;
        #pragma unroll
        for (int r = 0; r < NROWS; ++r) {
            const float top = v[r][lo], bot = v[r][hi];
            v[r][lo] = w[pc].x * top + w[pc].y * bot;
            v[r][hi] = w[pc].z * top + w[pc].w * bot;
        }
    }
}

// ---- Prepass: layers 3..11 -> lane-coalesced nws[(l-3)*2048 + pc*512 + t].
// Thread-role per stage: s=1:(d3,d1,d0) pairs d2; s=2:(d3,d2,d0) pairs d1;
// s=3:(d3,d2,d1) pairs d0. Twiddle src = delete bit B=11-l from element index.
__global__ __launch_bounds__(256)
void permute_tw8(const float* __restrict__ tw, float4* __restrict__ nws) {
    const int i = blockIdx.x * 256 + threadIdx.x;   // 0 .. 18431
    const int li = i >> 11;          // 0..8 -> layer 3+li
    const int j  = i & 2047;
    const int pc = j >> 9;           // 0..3
    const int t  = j & 511;
    const int l  = 3 + li;
    const int s  = l / 3, k = l % 3, B = 11 - l;
    const int bit = 2 - k, d = 1 << bit;
    const int lo = ((pc >> bit) << (bit + 1)) | (pc & (d - 1));
    int d3, d2, d1, d0;
    if (s == 1)      { d3 = t >> 6; d1 = (t >> 3) & 7; d0 = t & 7; d2 = lo; }
    else if (s == 2) { d3 = t >> 6; d2 = (t >> 3) & 7; d0 = t & 7; d1 = lo; }
    else             { d3 = t >> 6; d2 = (t >> 3) & 7; d1 = t & 7; d0 = lo; }
    const int e = (d3 << 9) | (d2 << 6) | (d1 << 3) | d0;
    const int src = ((e >> (B + 1)) << B) | (e & ((1 << B) - 1));
    nws[i] = ((const float4*)tw)[l * 2048 + src];
}

// ---- Main radix-8 kernel: 512 threads, 4 rows, 8 elems/thread.
// launch_bounds(512,4): empirical VGPR cap = 64 (law from R3/R5/R7: 256-blocks
// cap ~256/arg -> generalized 512/(arg*B/256)). Live state ~60 -> no spill,
// and 64-VGPR bucket -> up to 8 waves/SIMD (vs 4 at 84 VGPR) for the latency-
// bound regime R9 exposed. LDS 34.8KB -> 4 blocks/CU, occupancy cap 100%.
__global__ __launch_bounds__(512, 4)
void bfly8_kernel(const float* __restrict__ x,
                  const float* __restrict__ tw,
                  const float4* __restrict__ nws,
                  float* __restrict__ out) {
    __shared__ float lds[2 * ROWBUF];   // 34816 B: 2-row transpose batches
    const int t = threadIdx.x;          // 0..511
    const int row0 = blockIdx.x * NROWS;
    const float4* tw4 = (const float4*)tw;

    float v[NROWS][8];

    // Load: v[r][d3] = x[row, d3*512 + t]  (lane-consecutive dword per d3)
    #pragma unroll
    for (int r = 0; r < NROWS; ++r) {
        const float* xr = x + (size_t)(row0 + r) * N + t;
        #pragma unroll
        for (int d3 = 0; d3 < 8; ++d3)
            v[r][d3] = __builtin_nontemporal_load(xr + d3 * 512);
    }

    // Stage 0: layers 0..2 (pairs in d3). Natural layout is lane-coalesced:
    // idx = l*2048 + pc*512 + t for all three sub-layers (derived; bit B=11-l).
    #pragma unroll
    for (int k = 0; k < 3; ++k) {
        float4 w[4];
        #pragma unroll
        for (int pc = 0; pc < 4; ++pc)
            w[pc] = tw4[k * 2048 + pc * 512 + t];
        bfly(v, w, k);
    }

    // T1: write over d3 (stride-1), read over d2 (2-way, pad-68). 2-row batches.
    // Unified layout: idx(d3,d2,d1,d0) = d3*544 + d2*68 + d1*8 + d0.
    #pragma unroll
    for (int h = 0; h < 2; ++h) {
        #pragma unroll
        for (int rr = 0; rr < 2; ++rr) {
            float* buf = lds + rr * ROWBUF;
            const int base = ((t >> 6) * D2S) + (t & 63);   // (d2, d1d0)
            #pragma unroll
            for (int d3 = 0; d3 < 8; ++d3)
                buf[d3 * D3S + base] = v[2 * h + rr][d3];
        }
        __syncthreads();
        #pragma unroll
        for (int rr = 0; rr < 2; ++rr) {
            const float* buf = lds + rr * ROWBUF;
            const int base = ((t >> 6) * D3S) + (t & 63);   // (d3, d1d0)
            #pragma unroll
            for (int d2 = 0; d2 < 8; ++d2)
                v[2 * h + rr][d2] = buf[base + d2 * D2S];
        }
        __syncthreads();
    }

    // Stage 1: layers 3..5 (pairs in d2), coalesced permuted twiddles
    #pragma unroll
    for (int k = 0; k < 3; ++k) {
        float4 w[4];
        #pragma unroll
        for (int pc = 0; pc < 4; ++pc)
            w[pc] = nws[(k) * 2048 + pc * 512 + t];         // layers 3..5
        bfly(v, w, k);
    }

    // T2: write over d2 (stride-1), read over d1 (2-way)
    #pragma unroll
    for (int h = 0; h < 2; ++h) {
        #pragma unroll
        for (int rr = 0; rr < 2; ++rr) {
            float* buf = lds + rr * ROWBUF;
            const int base = ((t >> 6) * D3S) + (t & 63);   // (d3, d1d0)
            #pragma unroll
            for (int d2 = 0; d2 < 8; ++d2)
                buf[base + d2 * D2S] = v[2 * h + rr][d2];
        }
        __syncthreads();
        #pragma unroll
        for (int rr = 0; rr < 2; ++rr) {
            const float* buf = lds + rr * ROWBUF;
            const int base = ((t >> 6) * D3S) + (((t >> 3) & 7) * D2S) + (t & 7); // (d3,d2,d0)
            #pragma unroll
            for (int d1 = 0; d1 < 8; ++d1)
                v[2 * h + rr][d1] = buf[base + d1 * 8];
        }
        __syncthreads();
    }

    // Stage 2: layers 6..8 (pairs in d1)
    #pragma unroll
    for (int k = 0; k < 3; ++k) {
        float4 w[4];
        #pragma unroll
        for (int pc = 0; pc < 4; ++pc)
            w[pc] = nws[(3 + k) * 2048 + pc * 512 + t];     // layers 6..8
        bfly(v, w, k);
    }

    // T3: write over d1 (2-way), read d0-contiguous as 2x b128 (aligned, 2-way)
    #pragma unroll
    for (int h = 0; h < 2; ++h) {
        #pragma unroll
        for (int rr = 0; rr < 2; ++rr) {
            float* buf = lds + rr * ROWBUF;
            const int base = ((t >> 6) * D3S) + (((t >> 3) & 7) * D2S) + (t & 7); // (d3,d2,d0)
            #pragma unroll
            for (int d1 = 0; d1 < 8; ++d1)
                buf[base + d1 * 8] = v[2 * h + rr][d1];
        }
        __syncthreads();
        #pragma unroll
        for (int rr = 0; rr < 2; ++rr) {
            const float* buf = lds + rr * ROWBUF;
            const int base = ((t >> 6) * D3S) + (((t >> 3) & 7) * D2S) + ((t & 7) * 8); // (d3,d2,d1)
            v4f lo4 = *(const v4f*)(buf + base);
            v4f hi4 = *(const v4f*)(buf + base + 4);
            float (&vr)[8] = v[2 * h + rr];
            vr[0] = lo4.x; vr[1] = lo4.y; vr[2] = lo4.z; vr[3] = lo4.w;
            vr[4] = hi4.x; vr[5] = hi4.y; vr[6] = hi4.z; vr[7] = hi4.w;
        }
        if (h == 0) __syncthreads();
    }

    // Stage 3: layers 9..11 (pairs in d0)
    #pragma unroll
    for (int k = 0; k < 3; ++k) {
        float4 w[4];
        #pragma unroll
        for (int pc = 0; pc < 4; ++pc)
            w[pc] = nws[(6 + k) * 2048 + pc * 512 + t];     // layers 9..11
        bfly(v, w, k);
    }

    // Store: thread holds floats [8t, 8t+8) of each row -> 2x b128, lanes 32B
    // apart (2 lanes per 64B sector; L2 merges; request count 2x minimal, far
    // under the request budget). Plain write-back stores (R2 lesson: no nt on
    // partial sectors).
    #pragma unroll
    for (int r = 0; r < NROWS; ++r) {
        float* orow = out + (size_t)(row0 + r) * N + 8 * t;
        v4f s0, s1;
        s0.x = v[r][0]; s0.y = v[r][1]; s0.z = v[r][2]; s0.w = v[r][3];
        s1.x = v[r][4]; s1.y = v[r][5]; s1.z = v[r][6]; s1.w = v[r][7];
        *(v4f*)(orow)     = s0;
        *(v4f*)(orow + 4) = s1;
    }
}

// ---- Fallback (no-workspace, R6 structure) if ws is too small for prepass
#define PAD_STRIDE 264
#define BUF_WORDS (16 * PAD_STRIDE)

__device__ __forceinline__ void layer16(float (&v)[4][16], const float4 (&w)[8], const int bit) {
    const int d = 1 << bit;
    #pragma unroll
    for (int pc = 0; pc < 8; ++pc) {
        const int lo = ((pc >> bit) << (bit + 1)) | (pc & (d - 1));
        const int hi = lo + d;
        #pragma unroll
        for (int r = 0; r < 4; ++r) {
            const float top = v[r][lo], bot = v[r][hi];
            v[r][lo] = w[pc].x * top + w[pc].y * bot;
            v[r][hi] = w[pc].z * top + w[pc].w * bot;
        }
    }
}

__global__ __launch_bounds__(256, 3)
void butterfly_kernel_fb(const float* __restrict__ x,
                         const float* __restrict__ tw,
                         float* __restrict__ out) {
    __shared__ float lds[BUF_WORDS];
    const int t = threadIdx.x;
    const int thi = t >> 4, tlo = t & 15;
    const int row0 = blockIdx.x * 4;
    const float4* tw4 = (const float4*)tw;
    float v[4][16];
    #pragma unroll
    for (int r = 0; r < 4; ++r) {
        const float* xr = x + (size_t)(row0 + r) * N + t;
        #pragma unroll
        for (int a = 0; a < 16; ++a) v[r][a] = __builtin_nontemporal_load(xr + a * 256);
    }
    #pragma unroll
    for (int l = 0; l < 4; ++l) {
        float4 w[8];
        #pragma unroll
        for (int pc = 0; pc < 8; ++pc) w[pc] = tw4[l * 2048 + pc * 256 + t];
        layer16(v, w, 3 - l);
    }
    #pragma unroll
    for (int r = 0; r < 4; ++r) {
        #pragma unroll
        for (int a = 0; a < 16; ++a) lds[a * PAD_STRIDE + t] = v[r][a];
        __syncthreads();
        #pragma unroll
        for (int b = 0; b < 16; ++b) v[r][b] = lds[thi * PAD_STRIDE + b * 16 + tlo];
        __syncthreads();
    }
    #pragma unroll
    for (int l = 4; l < 8; ++l) {
        float4 w[8];
        #pragma unroll
        for (int pc = 0; pc < 8; ++pc) w[pc] = tw4[l * 2048 + thi * 128 + pc * 16 + tlo];
        layer16(v, w, 3 - (l - 4));
    }
    #pragma unroll
    for (int r = 0; r < 4; ++r) {
        #pragma unroll
        for (int b = 0; b < 16; ++b) lds[thi * PAD_STRIDE + b * 16 + tlo] = v[r][b];
        __syncthreads();
        const float* bp = &lds[thi * PAD_STRIDE + tlo * 16];
        #pragma unroll
        for (int q = 0; q < 4; ++q) {
            v4f c4 = *(const v4f*)(bp + 4 * q);
            v[r][4 * q + 0] = c4.x; v[r][4 * q + 1] = c4.y;
            v[r][4 * q + 2] = c4.z; v[r][4 * q + 3] = c4.w;
        }
        if (r != 3) __syncthreads();
    }
    #pragma unroll
    for (int l = 8; l < 12; ++l) {
        float4 w[8];
        #pragma unroll
        for (int pc = 0; pc < 8; ++pc) w[pc] = tw4[l * 2048 + thi * 128 + tlo * 8 + pc];
        layer16(v, w, 3 - (l - 8));
    }
    #pragma unroll
    for (int r = 0; r < 4; ++r) {
        float* orow = out + (size_t)(row0 + r) * N + 16 * t;
        #pragma unroll
        for (int q = 0; q < 4; ++q) {
            v4f s4;
            s4.x = v[r][4 * q + 0]; s4.y = v[r][4 * q + 1];
            s4.z = v[r][4 * q + 2]; s4.w = v[r][4 * q + 3];
            *(v4f*)(orow + 4 * q) = s4;
        }
    }
}

extern "C" void kernel_launch(void* const* d_in, const int* in_sizes, int n_in,
                              void* d_out, int out_size, void* d_ws, size_t ws_size,
                              hipStream_t stream) {
    const float* x  = (const float*)d_in[0];
    const float* tw = (const float*)d_in[1];
    float* out      = (float*)d_out;
    if (ws_size >= (size_t)NWS_F4 * 16u) {
        float4* nws = (float4*)d_ws;
        hipLaunchKernelGGL(permute_tw8, dim3(NWS_F4 * 16 / 4096), dim3(256), 0, stream, tw, nws);
        hipLaunchKernelGGL(bfly8_kernel, dim3(BATCH / NROWS), dim3(TPB), 0, stream,
                           x, tw, nws, out);
    } else {
        hipLaunchKernelGGL(butterfly_kernel_fb, dim3(BATCH / 4), dim3(256), 0, stream,
                           x, tw, out);
    }
}

// Round 11
// 76.730 us; speedup vs baseline: 1.1214x; 1.1214x over previous
//
#include <hip/hip_runtime.h>

#define ROWS 4
#define N 4096
#define BATCH 8192
#define S_AB 264            // T_AB row stride (floats): 256+8, 2-way banks max
#define HALF 5248           // floats per half-arena (= 16*328); two halves = 41984 B
#define S_BC 328            // T_BC a-stride (floats): 16*20 + 8, b128 bases spread
#define NWS_F4 (8 * 2048)   // permuted twiddles, layers 4..11

typedef float v4f __attribute__((ext_vector_type(4)));

__device__ __forceinline__ void layer_compute(float (&v)[ROWS][16],
                                              const float4 (&w)[8],
                                              const int bit) {
    const int d = 1 << bit;
    #pragma unroll
    for (int pc = 0; pc < 8; ++pc) {
        const int lo = ((pc >> bit) << (bit + 1)) | (pc & (d - 1));
        const int hi = lo + d;
        #pragma unroll
        for (int r = 0; r < ROWS; ++r) {
            const float top = v[r][lo];
            const float bot = v[r][hi];
            v[r][lo] = w[pc].x * top + w[pc].y * bot;
            v[r][hi] = w[pc].z * top + w[pc].w * bot;
        }
    }
}

// ---- Prepass (unchanged from R9): layers 4..11 -> lane-coalesced nws.
__global__ __launch_bounds__(256)
void permute_tw_kernel(const float* __restrict__ tw, float4* __restrict__ nws) {
    const int i = blockIdx.x * 256 + threadIdx.x;   // 0 .. 16383
    const int s  = i >> 11;                         // slot 0..7 -> layer 4+s
    const int j  = i & 2047;
    const int pc = j >> 8;
    const int a  = (j >> 4) & 15;
    const int cb = j & 15;
    const float4* tw4 = (const float4*)tw;
    const int src = (s < 4) ? (a * 128 + pc * 16 + cb)   // stage B layers 4..7
                            : (a * 128 + cb * 8 + pc);   // stage C layers 8..11
    nws[i] = tw4[(4 + s) * 2048 + src];
}

// launch_bounds(256,2): empirical VGPR-cap law on this toolchain is
// ~256/min_waves (R3..R8: 3->84, 4->64, 5->48). Cap 128 covers the ~110 live
// regs (64 data + 32 hoisted twiddles + temps) without spilling.
__global__ __launch_bounds__(256, 2)
void butterfly_kernel(const float* __restrict__ x,
                      const float* __restrict__ tw,
                      const float4* __restrict__ nws,
                      float* __restrict__ out) {
    __shared__ float lds[2 * HALF];     // 41984 B arena, two 21KB halves
    float* bufA = lds;
    float* bufB = lds + HALF;
    const int t   = threadIdx.x;
    const int thi = t >> 4;
    const int tlo = t & 15;
    const int row0 = blockIdx.x * ROWS;

    const float4* tw4 = (const float4*)tw;

    float v[ROWS][16];

    // ---- Load: v[r][a] = x[row, a*256 + t]  (coalesced dword per a)
    #pragma unroll
    for (int r = 0; r < ROWS; ++r) {
        const float* xr = x + (size_t)(row0 + r) * N + t;
        #pragma unroll
        for (int a = 0; a < 16; ++a)
            v[r][a] = __builtin_nontemporal_load(xr + a * 256);
    }

    // ---- Stage A: layers 0..3 (pairs in a); natural layout is coalesced
    #pragma unroll
    for (int l = 0; l < 4; ++l) {
        float4 w[8];
        #pragma unroll
        for (int pc = 0; pc < 8; ++pc)
            w[pc] = tw4[l * 2048 + pc * 256 + t];
        layer_compute(v, w, 3 - l);
    }

    // ---- Transpose A->B, 2-row batches; hoist layer-4 twiddles over barrier 1.
    // Write [a][bc] stride 264 (2-way free both sides).
    float4 wB[8];
    {
        #pragma unroll
        for (int a = 0; a < 16; ++a) bufA[a * S_AB + t] = v[0][a];
        #pragma unroll
        for (int a = 0; a < 16; ++a) bufB[a * S_AB + t] = v[1][a];
        #pragma unroll
        for (int pc = 0; pc < 8; ++pc)              // layer-4 loads fly over drain
            wB[pc] = nws[pc * 256 + t];
        __syncthreads();
        #pragma unroll
        for (int b = 0; b < 16; ++b) v[0][b] = bufA[thi * S_AB + b * 16 + tlo];
        #pragma unroll
        for (int b = 0; b < 16; ++b) v[1][b] = bufB[thi * S_AB + b * 16 + tlo];
        __syncthreads();
        #pragma unroll
        for (int a = 0; a < 16; ++a) bufA[a * S_AB + t] = v[2][a];
        #pragma unroll
        for (int a = 0; a < 16; ++a) bufB[a * S_AB + t] = v[3][a];
        __syncthreads();
        #pragma unroll
        for (int b = 0; b < 16; ++b) v[2][b] = bufA[thi * S_AB + b * 16 + tlo];
        #pragma unroll
        for (int b = 0; b < 16; ++b) v[3][b] = bufB[thi * S_AB + b * 16 + tlo];
    }

    // ---- Stage B: layer 4 from hoisted regs; 5..7 inline (coalesced nws)
    layer_compute(v, wB, 3);
    #pragma unroll
    for (int l = 5; l < 8; ++l) {
        float4 w[8];
        #pragma unroll
        for (int pc = 0; pc < 8; ++pc)
            w[pc] = nws[(l - 4) * 2048 + pc * 256 + t];
        layer_compute(v, w, 3 - (l - 4));
    }

    // ---- Transpose B->C, 2-row batches. Layout addr = a*328 + b*20 + c:
    // writes 2-way free; b128 reads at base (2a+5b+q)%8 -> all 8 base slots
    // (old 264/16 layout used only 4 -> half LDS width; part of the 2.6M base
    // conflicts). Hoist layer-8 twiddles over the first barrier.
    float4 wC[8];
    {
        __syncthreads();                            // T_AB reads done
        #pragma unroll
        for (int b = 0; b < 16; ++b) bufA[thi * S_BC + b * 20 + tlo] = v[0][b];
        #pragma unroll
        for (int b = 0; b < 16; ++b) bufB[thi * S_BC + b * 20 + tlo] = v[1][b];
        #pragma unroll
        for (int pc = 0; pc < 8; ++pc)              // layer-8 loads fly over drain
            wC[pc] = nws[4 * 2048 + pc * 256 + t];
        __syncthreads();
        #pragma unroll
        for (int rr = 0; rr < 2; ++rr) {
            const float* bp = (rr ? bufB : bufA) + thi * S_BC + tlo * 20;
            #pragma unroll
            for (int q = 0; q < 4; ++q) {
                v4f c4 = *(const v4f*)(bp + 4 * q);
                v[rr][4 * q + 0] = c4.x; v[rr][4 * q + 1] = c4.y;
                v[rr][4 * q + 2] = c4.z; v[rr][4 * q + 3] = c4.w;
            }
        }
        __syncthreads();
        #pragma unroll
        for (int b = 0; b < 16; ++b) bufA[thi * S_BC + b * 20 + tlo] = v[2][b];
        #pragma unroll
        for (int b = 0; b < 16; ++b) bufB[thi * S_BC + b * 20 + tlo] = v[3][b];
        __syncthreads();
        #pragma unroll
        for (int rr = 2; rr < 4; ++rr) {
            const float* bp = (rr == 3 ? bufB : bufA) + thi * S_BC + tlo * 20;
            #pragma unroll
            for (int q = 0; q < 4; ++q) {
                v4f c4 = *(const v4f*)(bp + 4 * q);
                v[rr][4 * q + 0] = c4.x; v[rr][4 * q + 1] = c4.y;
                v[rr][4 * q + 2] = c4.z; v[rr][4 * q + 3] = c4.w;
            }
        }
    }

    // ---- Stage C: layer 8 from hoisted regs; 9..11 inline
    layer_compute(v, wC, 3);
    #pragma unroll
    for (int l = 9; l < 12; ++l) {
        float4 w[8];
        #pragma unroll
        for (int pc = 0; pc < 8; ++pc)
            w[pc] = nws[(l - 4) * 2048 + pc * 256 + t];
        layer_compute(v, w, 3 - (l - 8));
    }

    // ---- Store restage, 2 rows/batch, padded f4 layout: quad idx m lives at
    // f4[m + (m>>2)]. Write f4[5t+q]: b128 bases (5t+q)%8 hit all 8 slots
    // (old 4t+q hit 2 -> the 3.1M conflict delta, R9). Read f4[320k+t+(t>>2)]
    // (bijective), then 1KB/wave contiguous nontemporal stores (full sectors).
    {
        v4f* fA = (v4f*)bufA;
        v4f* fB = (v4f*)bufB;
        __syncthreads();                            // T_BC reads done
        #pragma unroll
        for (int h = 0; h < 2; ++h) {
            #pragma unroll
            for (int rr = 0; rr < 2; ++rr) {
                v4f* f = rr ? fB : fA;
                const int r = 2 * h + rr;
                #pragma unroll
                for (int q = 0; q < 4; ++q) {
                    v4f s4;
                    s4.x = v[r][4 * q + 0]; s4.y = v[r][4 * q + 1];
                    s4.z = v[r][4 * q + 2]; s4.w = v[r][4 * q + 3];
                    f[5 * t + q] = s4;
                }
            }
            __syncthreads();
            #pragma unroll
            for (int rr = 0; rr < 2; ++rr) {
                v4f* f = rr ? fB : fA;
                const int r = 2 * h + rr;
                float* orow = out + (size_t)(row0 + r) * N;
                #pragma unroll
                for (int k = 0; k < 4; ++k) {
                    const int m = k * 256 + t;
                    v4f s4 = f[m + (m >> 2)];
                    __builtin_nontemporal_store(s4, (v4f*)orow + m);
                }
            }
            if (h == 0) __syncthreads();
        }
    }
}

// ---- Fallback (R6 structure) if workspace too small for the prepass
#define PAD_STRIDE 264
#define BUF_WORDS (16 * PAD_STRIDE)

__global__ __launch_bounds__(256, 3)
void butterfly_kernel_fb(const float* __restrict__ x,
                         const float* __restrict__ tw,
                         float* __restrict__ out) {
    __shared__ float lds[BUF_WORDS];
    const int t = threadIdx.x;
    const int thi = t >> 4, tlo = t & 15;
    const int row0 = blockIdx.x * 4;
    const float4* tw4 = (const float4*)tw;
    float v[4][16];
    #pragma unroll
    for (int r = 0; r < 4; ++r) {
        const float* xr = x + (size_t)(row0 + r) * N + t;
        #pragma unroll
        for (int a = 0; a < 16; ++a) v[r][a] = __builtin_nontemporal_load(xr + a * 256);
    }
    #pragma unroll
    for (int l = 0; l < 4; ++l) {
        float4 w[8];
        #pragma unroll
        for (int pc = 0; pc < 8; ++pc) w[pc] = tw4[l * 2048 + pc * 256 + t];
        layer_compute(v, w, 3 - l);
    }
    #pragma unroll
    for (int r = 0; r < 4; ++r) {
        #pragma unroll
        for (int a = 0; a < 16; ++a) lds[a * PAD_STRIDE + t] = v[r][a];
        __syncthreads();
        #pragma unroll
        for (int b = 0; b < 16; ++b) v[r][b] = lds[thi * PAD_STRIDE + b * 16 + tlo];
        __syncthreads();
    }
    #pragma unroll
    for (int l = 4; l < 8; ++l) {
        float4 w[8];
        #pragma unroll
        for (int pc = 0; pc < 8; ++pc) w[pc] = tw4[l * 2048 + thi * 128 + pc * 16 + tlo];
        layer_compute(v, w, 3 - (l - 4));
    }
    #pragma unroll
    for (int r = 0; r < 4; ++r) {
        #pragma unroll
        for (int b = 0; b < 16; ++b) lds[thi * PAD_STRIDE + b * 16 + tlo] = v[r][b];
        __syncthreads();
        const float* bp = &lds[thi * PAD_STRIDE + tlo * 16];
        #pragma unroll
        for (int q = 0; q < 4; ++q) {
            v4f c4 = *(const v4f*)(bp + 4 * q);
            v[r][4 * q + 0] = c4.x; v[r][4 * q + 1] = c4.y;
            v[r][4 * q + 2] = c4.z; v[r][4 * q + 3] = c4.w;
        }
        if (r != 3) __syncthreads();
    }
    #pragma unroll
    for (int l = 8; l < 12; ++l) {
        float4 w[8];
        #pragma unroll
        for (int pc = 0; pc < 8; ++pc) w[pc] = tw4[l * 2048 + thi * 128 + tlo * 8 + pc];
        layer_compute(v, w, 3 - (l - 8));
    }
    #pragma unroll
    for (int r = 0; r < 4; ++r) {
        float* orow = out + (size_t)(row0 + r) * N + 16 * t;
        #pragma unroll
        for (int q = 0; q < 4; ++q) {
            v4f s4;
            s4.x = v[r][4 * q + 0]; s4.y = v[r][4 * q + 1];
            s4.z = v[r][4 * q + 2]; s4.w = v[r][4 * q + 3];
            *(v4f*)(orow + 4 * q) = s4;
        }
    }
}

extern "C" void kernel_launch(void* const* d_in, const int* in_sizes, int n_in,
                              void* d_out, int out_size, void* d_ws, size_t ws_size,
                              hipStream_t stream) {
    const float* x  = (const float*)d_in[0];
    const float* tw = (const float*)d_in[1];
    float* out      = (float*)d_out;
    dim3 block(256);
    if (ws_size >= (size_t)NWS_F4 * 16u) {
        float4* nws = (float4*)d_ws;
        hipLaunchKernelGGL(permute_tw_kernel, dim3(64), block, 0, stream, tw, nws);
        hipLaunchKernelGGL(butterfly_kernel, dim3(BATCH / ROWS), block, 0, stream,
                           x, tw, nws, out);
    } else {
        hipLaunchKernelGGL(butterfly_kernel_fb, dim3(BATCH / 4), block, 0, stream,
                           x, tw, out);
    }
}

// Round 12
// 66.710 us; speedup vs baseline: 1.2898x; 1.1502x over previous
//
#include <hip/hip_runtime.h>

#define ROWS 4
#define N 4096
#define BATCH 8192
#define S_AB 264            // arena row stride (floats): 256+8
#define ARENA 4224          // floats per arena (16*264); 2 arenas = 33792 B
#define NWS_F4 (8 * 2048)   // permuted twiddles, layers 4..11

typedef float v4f __attribute__((ext_vector_type(4)));

__device__ __forceinline__ void layer_compute(float (&v)[ROWS][16],
                                              const float4 (&w)[8],
                                              const int bit) {
    const int d = 1 << bit;
    #pragma unroll
    for (int pc = 0; pc < 8; ++pc) {
        const int lo = ((pc >> bit) << (bit + 1)) | (pc & (d - 1));
        const int hi = lo + d;
        #pragma unroll
        for (int r = 0; r < ROWS; ++r) {
            const float top = v[r][lo];
            const float bot = v[r][hi];
            v[r][lo] = w[pc].x * top + w[pc].y * bot;
            v[r][hi] = w[pc].z * top + w[pc].w * bot;
        }
    }
}

// ---- Prepass (unchanged): layers 4..11 -> lane-coalesced nws.
__global__ __launch_bounds__(256)
void permute_tw_kernel(const float* __restrict__ tw, float4* __restrict__ nws) {
    const int i = blockIdx.x * 256 + threadIdx.x;   // 0 .. 16383
    const int s  = i >> 11;                         // slot 0..7 -> layer 4+s
    const int j  = i & 2047;
    const int pc = j >> 8;
    const int a  = (j >> 4) & 15;
    const int cb = j & 15;
    const float4* tw4 = (const float4*)tw;
    const int src = (s < 4) ? (a * 128 + pc * 16 + cb)   // stage B layers 4..7
                            : (a * 128 + cb * 8 + pc);   // stage C layers 8..11
    nws[i] = tw4[(4 + s) * 2048 + src];
}

// (256,3): proven 84-VGPR spill-free envelope (R6/R9). LDS 33.8KB -> 4 blocks/CU.
__global__ __launch_bounds__(256, 3)
void butterfly_kernel(const float* __restrict__ x,
                      const float* __restrict__ tw,
                      const float4* __restrict__ nws,
                      float* __restrict__ out) {
    __shared__ float lds[2 * ARENA];
    float* bufA = lds;
    float* bufB = lds + ARENA;
    const int t   = threadIdx.x;
    const int thi = t >> 4;
    const int tlo = t & 15;
    const int row0 = blockIdx.x * ROWS;
    const float4* tw4 = (const float4*)tw;

    float v[ROWS][16];

    // ---- Stage-in: 16 dwordx4 global requests/thread (was 64 dword), through
    // linear LDS, read out stride-1 into (b,c)-all-a layout. Rows 2/3 loads are
    // issued before barrier 1 so HBM latency flies over the stage-in barriers.
    {
        const float* r0 = x + (size_t)(row0 + 0) * N + 4 * t;
        const float* r1 = x + (size_t)(row0 + 1) * N + 4 * t;
        const float* r2 = x + (size_t)(row0 + 2) * N + 4 * t;
        const float* r3 = x + (size_t)(row0 + 3) * N + 4 * t;
        v4f t0[4], t1[4];
        #pragma unroll
        for (int i = 0; i < 4; ++i) t0[i] = *(const v4f*)(r0 + i * 1024);
        #pragma unroll
        for (int i = 0; i < 4; ++i) t1[i] = *(const v4f*)(r1 + i * 1024);
        #pragma unroll
        for (int i = 0; i < 4; ++i) *(v4f*)(bufA + i * 1024 + 4 * t) = t0[i];
        #pragma unroll
        for (int i = 0; i < 4; ++i) *(v4f*)(bufB + i * 1024 + 4 * t) = t1[i];
        #pragma unroll
        for (int i = 0; i < 4; ++i) t0[i] = *(const v4f*)(r2 + i * 1024);  // in flight
        #pragma unroll
        for (int i = 0; i < 4; ++i) t1[i] = *(const v4f*)(r3 + i * 1024);  // across bars
        __syncthreads();
        #pragma unroll
        for (int a = 0; a < 16; ++a) v[0][a] = bufA[a * 256 + t];   // stride-1: free
        #pragma unroll
        for (int a = 0; a < 16; ++a) v[1][a] = bufB[a * 256 + t];
        __syncthreads();
        #pragma unroll
        for (int i = 0; i < 4; ++i) *(v4f*)(bufA + i * 1024 + 4 * t) = t0[i];
        #pragma unroll
        for (int i = 0; i < 4; ++i) *(v4f*)(bufB + i * 1024 + 4 * t) = t1[i];
        __syncthreads();
        #pragma unroll
        for (int a = 0; a < 16; ++a) v[2][a] = bufA[a * 256 + t];
        #pragma unroll
        for (int a = 0; a < 16; ++a) v[3][a] = bufB[a * 256 + t];
    }

    // ---- Stage A: layers 0..3 (pairs in a); natural twiddle layout coalesced
    #pragma unroll
    for (int l = 0; l < 4; ++l) {
        float4 w[8];
        #pragma unroll
        for (int pc = 0; pc < 8; ++pc)
            w[pc] = tw4[l * 2048 + pc * 256 + t];
        layer_compute(v, w, 3 - l);
    }

    // ---- Transpose A->B, 2-row batches (write stride-1, read 2-way: free)
    __syncthreads();                                // stage-in reads complete
    #pragma unroll
    for (int a = 0; a < 16; ++a) bufA[a * S_AB + t] = v[0][a];
    #pragma unroll
    for (int a = 0; a < 16; ++a) bufB[a * S_AB + t] = v[1][a];
    __syncthreads();
    #pragma unroll
    for (int b = 0; b < 16; ++b) v[0][b] = bufA[thi * S_AB + b * 16 + tlo];
    #pragma unroll
    for (int b = 0; b < 16; ++b) v[1][b] = bufB[thi * S_AB + b * 16 + tlo];
    __syncthreads();
    #pragma unroll
    for (int a = 0; a < 16; ++a) bufA[a * S_AB + t] = v[2][a];
    #pragma unroll
    for (int a = 0; a < 16; ++a) bufB[a * S_AB + t] = v[3][a];
    __syncthreads();
    #pragma unroll
    for (int b = 0; b < 16; ++b) v[2][b] = bufA[thi * S_AB + b * 16 + tlo];
    #pragma unroll
    for (int b = 0; b < 16; ++b) v[3][b] = bufB[thi * S_AB + b * 16 + tlo];

    // ---- Stage B: layers 4..7 (pairs in b); coalesced permuted twiddles
    #pragma unroll
    for (int l = 4; l < 8; ++l) {
        float4 w[8];
        #pragma unroll
        for (int pc = 0; pc < 8; ++pc)
            w[pc] = nws[(l - 4) * 2048 + pc * 256 + t];
        layer_compute(v, w, 3 - (l - 4));
    }

    // ---- Transpose B->C, compact q-XOR layout in the 264-stride arena.
    // Elem (a,b,c) at a*264 + b*16 + 4*((c>>2)^(b&3)) + (c&3).
    // Writes: bank (8thi + 4((tlo>>2)^(b&3)) + (tlo&3))%32 -> 2-way (free).
    // b128 reads: slot (2thi + 4(tlo&1) + q^(tlo&3))%8 -> 8 lanes/slot (minimum).
    {
        __syncthreads();                            // T_AB reads done
        #pragma unroll
        for (int b = 0; b < 16; ++b) {
            const int coff = 4 * (((tlo >> 2) ^ (b & 3))) + (tlo & 3);
            bufA[thi * S_AB + b * 16 + coff] = v[0][b];
            bufB[thi * S_AB + b * 16 + coff] = v[1][b];
        }
        __syncthreads();
        #pragma unroll
        for (int rr = 0; rr < 2; ++rr) {
            const float* bp = (rr ? bufB : bufA) + thi * S_AB + tlo * 16;
            #pragma unroll
            for (int q = 0; q < 4; ++q) {
                v4f c4 = *(const v4f*)(bp + 4 * (q ^ (tlo & 3)));
                v[rr][4 * q + 0] = c4.x; v[rr][4 * q + 1] = c4.y;
                v[rr][4 * q + 2] = c4.z; v[rr][4 * q + 3] = c4.w;
            }
        }
        __syncthreads();
        #pragma unroll
        for (int b = 0; b < 16; ++b) {
            const int coff = 4 * (((tlo >> 2) ^ (b & 3))) + (tlo & 3);
            bufA[thi * S_AB + b * 16 + coff] = v[2][b];
            bufB[thi * S_AB + b * 16 + coff] = v[3][b];
        }
        __syncthreads();
        #pragma unroll
        for (int rr = 2; rr < 4; ++rr) {
            const float* bp = (rr == 3 ? bufB : bufA) + thi * S_AB + tlo * 16;
            #pragma unroll
            for (int q = 0; q < 4; ++q) {
                v4f c4 = *(const v4f*)(bp + 4 * (q ^ (tlo & 3)));
                v[rr][4 * q + 0] = c4.x; v[rr][4 * q + 1] = c4.y;
                v[rr][4 * q + 2] = c4.z; v[rr][4 * q + 3] = c4.w;
            }
        }
    }

    // ---- Stage C: layers 8..11 (pairs in c)
    #pragma unroll
    for (int l = 8; l < 12; ++l) {
        float4 w[8];
        #pragma unroll
        for (int pc = 0; pc < 8; ++pc)
            w[pc] = nws[(l - 4) * 2048 + pc * 256 + t];
        layer_compute(v, w, 3 - (l - 8));
    }

    // ---- Store restage, compact XOR layout (fits 4096 floats of the arena):
    // owner T writes quad Q at f4[4T + (Q ^ ((T>>2)&3))] -> 8 lanes/slot (free);
    // reader wants logical quad j=k*256+t at f4[(j&~3) | ((j&3)^((j>>4)&3))]
    // -> 8 lanes/slot (free). Then 1KB/wave contiguous nontemporal stores.
    {
        v4f* fA = (v4f*)bufA;
        v4f* fB = (v4f*)bufB;
        const int wsel = (t >> 2) & 3;
        __syncthreads();                            // T_BC reads done
        #pragma unroll
        for (int h = 0; h < 2; ++h) {
            #pragma unroll
            for (int rr = 0; rr < 2; ++rr) {
                v4f* f = rr ? fB : fA;
                const int r = 2 * h + rr;
                #pragma unroll
                for (int q = 0; q < 4; ++q) {
                    v4f s4;
                    s4.x = v[r][4 * q + 0]; s4.y = v[r][4 * q + 1];
                    s4.z = v[r][4 * q + 2]; s4.w = v[r][4 * q + 3];
                    f[4 * t + (q ^ wsel)] = s4;
                }
            }
            __syncthreads();
            #pragma unroll
            for (int rr = 0; rr < 2; ++rr) {
                v4f* f = rr ? fB : fA;
                const int r = 2 * h + rr;
                float* orow = out + (size_t)(row0 + r) * N;
                #pragma unroll
                for (int k = 0; k < 4; ++k) {
                    const int j = k * 256 + t;
                    v4f s4 = f[(j & ~3) | ((j & 3) ^ ((j >> 4) & 3))];
                    __builtin_nontemporal_store(s4, (v4f*)orow + j);
                }
            }
            if (h == 0) __syncthreads();
        }
    }
}

// ---- Fallback (R6 structure) if workspace too small for the prepass
#define PAD_STRIDE 264
#define BUF_WORDS (16 * PAD_STRIDE)

__global__ __launch_bounds__(256, 3)
void butterfly_kernel_fb(const float* __restrict__ x,
                         const float* __restrict__ tw,
                         float* __restrict__ out) {
    __shared__ float lds[BUF_WORDS];
    const int t = threadIdx.x;
    const int thi = t >> 4, tlo = t & 15;
    const int row0 = blockIdx.x * 4;
    const float4* tw4 = (const float4*)tw;
    float v[4][16];
    #pragma unroll
    for (int r = 0; r < 4; ++r) {
        const float* xr = x + (size_t)(row0 + r) * N + t;
        #pragma unroll
        for (int a = 0; a < 16; ++a) v[r][a] = __builtin_nontemporal_load(xr + a * 256);
    }
    #pragma unroll
    for (int l = 0; l < 4; ++l) {
        float4 w[8];
        #pragma unroll
        for (int pc = 0; pc < 8; ++pc) w[pc] = tw4[l * 2048 + pc * 256 + t];
        layer_compute(v, w, 3 - l);
    }
    #pragma unroll
    for (int r = 0; r < 4; ++r) {
        #pragma unroll
        for (int a = 0; a < 16; ++a) lds[a * PAD_STRIDE + t] = v[r][a];
        __syncthreads();
        #pragma unroll
        for (int b = 0; b < 16; ++b) v[r][b] = lds[thi * PAD_STRIDE + b * 16 + tlo];
        __syncthreads();
    }
    #pragma unroll
    for (int l = 4; l < 8; ++l) {
        float4 w[8];
        #pragma unroll
        for (int pc = 0; pc < 8; ++pc) w[pc] = tw4[l * 2048 + thi * 128 + pc * 16 + tlo];
        layer_compute(v, w, 3 - (l - 4));
    }
    #pragma unroll
    for (int r = 0; r < 4; ++r) {
        #pragma unroll
        for (int b = 0; b < 16; ++b) lds[thi * PAD_STRIDE + b * 16 + tlo] = v[r][b];
        __syncthreads();
        const float* bp = &lds[thi * PAD_STRIDE + tlo * 16];
        #pragma unroll
        for (int q = 0; q < 4; ++q) {
            v4f c4 = *(const v4f*)(bp + 4 * q);
            v[r][4 * q + 0] = c4.x; v[r][4 * q + 1] = c4.y;
            v[r][4 * q + 2] = c4.z; v[r][4 * q + 3] = c4.w;
        }
        if (r != 3) __syncthreads();
    }
    #pragma unroll
    for (int l = 8; l < 12; ++l) {
        float4 w[8];
        #pragma unroll
        for (int pc = 0; pc < 8; ++pc) w[pc] = tw4[l * 2048 + thi * 128 + tlo * 8 + pc];
        layer_compute(v, w, 3 - (l - 8));
    }
    #pragma unroll
    for (int r = 0; r < 4; ++r) {
        float* orow = out + (size_t)(row0 + r) * N + 16 * t;
        #pragma unroll
        for (int q = 0; q < 4; ++q) {
            v4f s4;
            s4.x = v[r][4 * q + 0]; s4.y = v[r][4 * q + 1];
            s4.z = v[r][4 * q + 2]; s4.w = v[r][4 * q + 3];
            *(v4f*)(orow + 4 * q) = s4;
        }
    }
}

extern "C" void kernel_launch(void* const* d_in, const int* in_sizes, int n_in,
                              void* d_out, int out_size, void* d_ws, size_t ws_size,
                              hipStream_t stream) {
    const float* x  = (const float*)d_in[0];
    const float* tw = (const float*)d_in[1];
    float* out      = (float*)d_out;
    dim3 block(256);
    if (ws_size >= (size_t)NWS_F4 * 16u) {
        float4* nws = (float4*)d_ws;
        hipLaunchKernelGGL(permute_tw_kernel, dim3(64), block, 0, stream, tw, nws);
        hipLaunchKernelGGL(butterfly_kernel, dim3(BATCH / ROWS), block, 0, stream,
                           x, tw, nws, out);
    } else {
        hipLaunchKernelGGL(butterfly_kernel_fb, dim3(BATCH / 4), block, 0, stream,
                           x, tw, out);
    }
}